// Round 14
// baseline (228.614 us; speedup 1.0000x reference)
//
#include <hip/hip_runtime.h>

#define N_NODES 50000
#define N_EDGES 800000
#define NBUK    392          // buckets of 128 nodes: dst>>7
#define B_A     1024         // phase-A blocks
#define EPB     782          // edges per phase-A block (1024*782 >= 800000)
#define CAPB    2560         // fixed csr slot per 128-node bucket (mean 2041)
#define SLAB32  (N_NODES * 16)   // u32s per 32-channel slab (3.2 MB < 4MB XCD L2)
#define SLAB16  (N_NODES * 32)   // u16s per 32-channel slab
#define TILES   782              // 64-node tiles

typedef unsigned short u16;
typedef unsigned int   u32;
typedef __bf16 bf16x8 __attribute__((ext_vector_type(8)));
typedef float  f32x4  __attribute__((ext_vector_type(4)));

__device__ __forceinline__ float bf_lo(u32 v){ return __uint_as_float(v << 16); }
__device__ __forceinline__ float bf_hi(u32 v){ return __uint_as_float(v & 0xffff0000u); }
__device__ __forceinline__ u32 bf_pack(float a, float b){
    u32 ua = __float_as_uint(a), ub = __float_as_uint(b);
    ua += 0x7fffu + ((ua >> 16) & 1u);
    ub += 0x7fffu + ((ub >> 16) & 1u);
    return (ua >> 16) | (ub & 0xffff0000u);
}
__device__ __forceinline__ u16 f2bf(float a){
    u32 ua = __float_as_uint(a);
    ua += 0x7fffu + ((ua >> 16) & 1u);
    return (u16)(ua >> 16);
}
__device__ __forceinline__ void addu4(uint4 v, float* a){
    a[0] += bf_lo(v.x); a[1] += bf_hi(v.x);
    a[2] += bf_lo(v.y); a[3] += bf_hi(v.y);
    a[4] += bf_lo(v.z); a[5] += bf_hi(v.z);
    a[6] += bf_lo(v.w); a[7] += bf_hi(v.w);
}

// inclusive block-scan, 256 threads (4 waves)
__device__ __forceinline__ int blockScan256(int v, int* ws, int t) {
    int lane = t & 63, w = t >> 6;
    #pragma unroll
    for (int off = 1; off < 64; off <<= 1) {
        int u = __shfl_up(v, off);
        if (lane >= off) v += u;
    }
    if (lane == 63) ws[w] = v;
    __syncthreads();
    int add = 0;
    for (int k = 0; k < w; k++) add += ws[k];
    return v + add;
}

// ---- binA: blocks [0,1024): bucket-sort own 782 edges (dst>>7) in LDS, linear
//      flush; grid-stride fp32->bf16 of x into 4 channel slabs.
//      Blocks [1024,1217): weight prep. Tables: [bucket][run], stride B_A.
__launch_bounds__(256)
__global__ void binA_kernel(const int* __restrict__ esrc, const int* __restrict__ edst,
                            u32* __restrict__ binned, int* __restrict__ startTab,
                            int* __restrict__ cntTab,
                            const float* __restrict__ xsrc, u32* __restrict__ xb,
                            const float* __restrict__ W1a, const float* __restrict__ W1b,
                            const float* __restrict__ W2a, const float* __restrict__ W2b,
                            const float* __restrict__ Wfc, const float* __restrict__ b2b,
                            const float* __restrict__ bfc,
                            u16* __restrict__ wt1a, u16* __restrict__ wt1b,
                            u16* __restrict__ wt2a,
                            float* __restrict__ Wc, float* __restrict__ bc) {
    int t = threadIdx.x, blk = blockIdx.x;
    if (blk >= B_A) {                    // ---- prep branch (193 blocks)
        int b = blk - B_A;
        if (b < 192) {
            int g  = b * 256 + t;
            int mi = g >> 14;
            int p  = g & 16383;
            int k  = p >> 7, m = p & 127;
            const float* src = (mi == 0) ? W1a : (mi == 1) ? W1b : W2a;
            u16* dst         = (mi == 0) ? wt1a : (mi == 1) ? wt1b : wt2a;
            dst[m * 128 + k] = f2bf(src[k * 128 + m]);
        } else {
            int j = t >> 1, o = t & 1;
            float s = 0.f;
            for (int k = 0; k < 128; k++)
                s += W2b[j * 128 + k] * Wfc[k * 2 + o];
            Wc[j * 2 + o] = s;
            if (t < 2) {
                float s2 = 0.f;
                for (int k = 0; k < 128; k++)
                    s2 += b2b[k] * Wfc[k * 2 + t];
                bc[t] = s2 + bfc[t];
            }
        }
        return;
    }
    __shared__ int hist[NBUK];
    __shared__ int cur[NBUK];
    __shared__ u32 ebuf[EPB];
    __shared__ int ws[4];
    int base = blk * EPB;
    for (int i = t; i < NBUK; i += 256) hist[i] = 0;
    __syncthreads();
    for (int i = t; i < EPB; i += 256) {
        int gi = base + i;
        if (gi < N_EDGES) atomicAdd(&hist[edst[gi] >> 7], 1);
    }
    __syncthreads();
    int c0 = 0, c1 = 0;
    if (t < 196) { c0 = hist[2 * t]; c1 = hist[2 * t + 1]; }
    int s2 = c0 + c1;
    int incl = blockScan256(s2, ws, t);
    int excl = incl - s2;
    if (t < 196) {
        startTab[(2 * t) * B_A + blk]     = excl;        // [bucket][run]
        cntTab[(2 * t) * B_A + blk]       = c0;
        cur[2 * t] = excl;
        startTab[(2 * t + 1) * B_A + blk] = excl + c0;
        cntTab[(2 * t + 1) * B_A + blk]   = c1;
        cur[2 * t + 1] = excl + c0;
    }
    __syncthreads();
    for (int i = t; i < EPB; i += 256) {
        int gi = base + i;
        if (gi < N_EDGES) {
            int d = edst[gi], s = esrc[gi];
            int p = atomicAdd(&cur[d >> 7], 1);
            ebuf[p] = (u32)s | ((u32)(d & 127) << 16);   // src(16b)|dst_local(7b)
        }
    }
    __syncthreads();
    for (int i = t; i < EPB; i += 256)               // linear flush
        binned[base + i] = ebuf[i];
    // fp32 x -> bf16 channel slabs (grid-stride)
    const int total = N_NODES * 64;
    for (int i = blk * 256 + t; i < total; i += B_A * 256) {
        float2 f = ((const float2*)xsrc)[i];
        int node = i >> 6, c2 = i & 63;
        xb[(c2 >> 4) * SLAB32 + node * 16 + (c2 & 15)] = bf_pack(f.x, f.y);
    }
}

// ---- binB: one block per 128-node bucket; thread t copies runs 4t..4t+3
//      (round-9 verified). Counting sort in LDS, flush csr + span.
__launch_bounds__(256)
__global__ void binB_kernel(const u32* __restrict__ binned, const int* __restrict__ startTab,
                            const int* __restrict__ cntTab,
                            int2* __restrict__ span, int* __restrict__ csr) {
    __shared__ u32 ebuf[CAPB];
    __shared__ int cbuf[CAPB];
    __shared__ int hist[128];
    __shared__ int cursor[128];
    __shared__ int ws[4];
    __shared__ int totsh;
    int b = blockIdx.x, t = threadIdx.x;
    int c4[4], rs4[4], s = 0;
    #pragma unroll
    for (int q = 0; q < 4; q++) {
        int run = t * 4 + q;
        c4[q]  = cntTab[b * B_A + run];               // coalesced
        rs4[q] = run * EPB + startTab[b * B_A + run];
        s += c4[q];
    }
    int incl = blockScan256(s, ws, t);
    int rb = incl - s;
    if (t == 255) totsh = incl;
    if (t < 128) hist[t] = 0;
    __syncthreads();
    #pragma unroll
    for (int q = 0; q < 4; q++) {                     // copy own runs (no search)
        int c = c4[q], rs = rs4[q];
        for (int k = 0; k < c; k++) {
            int p = rb + k;
            if (p < CAPB) ebuf[p] = binned[rs + k];
        }
        rb += c;
    }
    __syncthreads();
    int tot = totsh;
    if (tot > CAPB) tot = CAPB;
    for (int i = t; i < tot; i += 256)
        atomicAdd(&hist[ebuf[i] >> 16], 1);
    __syncthreads();
    int hv = (t < 128) ? hist[t] : 0;
    int hincl = blockScan256(hv, ws, t);
    int hexcl = hincl - hv;
    int gb = b * CAPB;
    if (t < 128) {
        cursor[t] = hexcl;
        int node = (b << 7) + t;
        if (node < N_NODES) span[node] = make_int2(gb + hexcl, gb + hexcl + hv);
    }
    __syncthreads();
    for (int i = t; i < tot; i += 256) {
        u32 e = ebuf[i];
        int p = atomicAdd(&cursor[e >> 16], 1);
        cbuf[p] = (int)(e & 0xFFFFu);
    }
    __syncthreads();
    for (int i = t; i < tot; i += 256)
        csr[gb + i] = cbuf[i];
}

// ---- agg: XCD-partitioned channel-slab aggregation --------------------------
// 3128 blocks = 8 (XCD round-robin) x 391. Block i -> XCD i%8 (dispatch
// heuristic); slab = (i%8)&3, tile = (i>>3)*2 + ((i%8)>>2). Each XCD only
// gathers from ONE 3.2MB slab -> fits its 4MB L2; compulsory FETCH drops from
// ~89MB (every XCD reads all 12.8MB) to ~26MB. 64 nodes x 32ch per block.
__launch_bounds__(256, 8)
__global__ void agg_kernel(const u32* __restrict__ xb,
                           const int2* __restrict__ span, const int* __restrict__ csr,
                           u32* __restrict__ outb, int n) {
    int i = blockIdx.x;
    int k = i & 7;
    int slab = k & 3;
    int tile = (i >> 3) * 2 + (k >> 2);               // 0..781
    int t = threadIdx.x;
    int w = t >> 6, lane = t & 63;
    int sub = lane >> 2, ch = lane & 3;               // node-in-wave, 16B chunk
    int node = tile * 64 + w * 16 + sub;
    if (node >= n) return;
    const uint4* sp = (const uint4*)(xb + (size_t)slab * SLAB32);
    int2 spn = span[node];
    int j = spn.x, jend = spn.y;
    float a[8] = {0.f,0.f,0.f,0.f,0.f,0.f,0.f,0.f};
    addu4(sp[(size_t)node * 4 + ch], a);              // self term
    for (; j + 4 <= jend; j += 4) {
        int s0 = csr[j], s1 = csr[j + 1], s2 = csr[j + 2], s3 = csr[j + 3];
        uint4 v0 = sp[(size_t)s0 * 4 + ch], v1 = sp[(size_t)s1 * 4 + ch];
        uint4 v2 = sp[(size_t)s2 * 4 + ch], v3 = sp[(size_t)s3 * 4 + ch];
        addu4(v0, a); addu4(v1, a); addu4(v2, a); addu4(v3, a);
    }
    for (; j < jend; j++)
        addu4(sp[(size_t)csr[j] * 4 + ch], a);
    uint4 pk = make_uint4(bf_pack(a[0], a[1]), bf_pack(a[2], a[3]),
                          bf_pack(a[4], a[5]), bf_pack(a[6], a[7]));
    ((uint4*)(outb + (size_t)slab * SLAB32))[(size_t)node * 4 + ch] = pk;
}

// ---- gemm1: h1 = relu(relu(agg@WA+bA)@WB+bB), slab-layout in/out -----------
__launch_bounds__(256, 4)
__global__ void gemm1_kernel(const u32* __restrict__ A,
                             const u16* __restrict__ WA, const float* __restrict__ bA,
                             const u16* __restrict__ WB, const float* __restrict__ bB,
                             u16* __restrict__ h1, int n) {
    __shared__ u16 As[64][136];
    int t = threadIdx.x;
    int row0 = blockIdx.x * 64;
    {   // load 64 rows from slab layout: thread t -> row t>>2, chunk t&3
        int rl = t >> 2, q = t & 3;
        int node = row0 + rl;
        #pragma unroll
        for (int slab = 0; slab < 4; slab++) {
            uint4 v = make_uint4(0, 0, 0, 0);
            if (node < n) v = ((const uint4*)(A + (size_t)slab * SLAB32))[(size_t)node * 4 + q];
            *(uint4*)&As[rl][slab * 32 + q * 8] = v;
        }
    }
    __syncthreads();
    int w = t >> 6, lane = t & 63;
    int lm = lane & 15, lq = lane >> 4;
    f32x4 acc[8];
    #pragma unroll
    for (int c = 0; c < 8; c++) acc[c] = (f32x4){0.f, 0.f, 0.f, 0.f};
    #pragma unroll
    for (int kk = 0; kk < 4; kk++) {
        bf16x8 af = *(const bf16x8*)&As[w * 16 + lm][kk * 32 + lq * 8];
        #pragma unroll
        for (int c = 0; c < 8; c++) {
            bf16x8 bf = *(const bf16x8*)(WA + (size_t)(c * 16 + lm) * 128 + kk * 32 + lq * 8);
            acc[c] = __builtin_amdgcn_mfma_f32_16x16x32_bf16(af, bf, acc[c], 0, 0, 0);
        }
    }
    #pragma unroll
    for (int c = 0; c < 8; c++) {
        int col = c * 16 + lm;
        float bcol = bA[col];
        #pragma unroll
        for (int r = 0; r < 4; r++) {
            float v = acc[c][r] + bcol;
            v = v > 0.f ? v : 0.f;
            As[w * 16 + lq * 4 + r][col] = f2bf(v);   // wave-private rows
        }
    }
    f32x4 acc2[8];
    #pragma unroll
    for (int c = 0; c < 8; c++) acc2[c] = (f32x4){0.f, 0.f, 0.f, 0.f};
    #pragma unroll
    for (int kk = 0; kk < 4; kk++) {
        bf16x8 af = *(const bf16x8*)&As[w * 16 + lm][kk * 32 + lq * 8];
        #pragma unroll
        for (int c = 0; c < 8; c++) {
            bf16x8 bf = *(const bf16x8*)(WB + (size_t)(c * 16 + lm) * 128 + kk * 32 + lq * 8);
            acc2[c] = __builtin_amdgcn_mfma_f32_16x16x32_bf16(af, bf, acc2[c], 0, 0, 0);
        }
    }
    #pragma unroll
    for (int c = 0; c < 8; c++) {
        int col = c * 16 + lm;
        float bcol = bB[col];
        int slab = col >> 5, cw = col & 31;
        #pragma unroll
        for (int r = 0; r < 4; r++) {
            int row = row0 + w * 16 + lq * 4 + r;
            if (row < n) {
                float v = acc2[c][r] + bcol;
                v = v > 0.f ? v : 0.f;
                h1[(size_t)slab * SLAB16 + (size_t)row * 32 + cw] = f2bf(v);
            }
        }
    }
}

// ---- gemm2fc: out = relu(agg@WA+bA) @ Wc + bc -------------------------------
__launch_bounds__(256, 4)
__global__ void gemm2fc_kernel(const u32* __restrict__ A,
                               const u16* __restrict__ WA, const float* __restrict__ bA,
                               const float* __restrict__ Wc, const float* __restrict__ bc,
                               float2* __restrict__ out, int n) {
    __shared__ u16 As[64][136];
    int t = threadIdx.x;
    int row0 = blockIdx.x * 64;
    {
        int rl = t >> 2, q = t & 3;
        int node = row0 + rl;
        #pragma unroll
        for (int slab = 0; slab < 4; slab++) {
            uint4 v = make_uint4(0, 0, 0, 0);
            if (node < n) v = ((const uint4*)(A + (size_t)slab * SLAB32))[(size_t)node * 4 + q];
            *(uint4*)&As[rl][slab * 32 + q * 8] = v;
        }
    }
    __syncthreads();
    int w = t >> 6, lane = t & 63;
    int lm = lane & 15, lq = lane >> 4;
    f32x4 acc[8];
    #pragma unroll
    for (int c = 0; c < 8; c++) acc[c] = (f32x4){0.f, 0.f, 0.f, 0.f};
    #pragma unroll
    for (int kk = 0; kk < 4; kk++) {
        bf16x8 af = *(const bf16x8*)&As[w * 16 + lm][kk * 32 + lq * 8];
        #pragma unroll
        for (int c = 0; c < 8; c++) {
            bf16x8 bf = *(const bf16x8*)(WA + (size_t)(c * 16 + lm) * 128 + kk * 32 + lq * 8);
            acc[c] = __builtin_amdgcn_mfma_f32_16x16x32_bf16(af, bf, acc[c], 0, 0, 0);
        }
    }
    float p0[4] = {0,0,0,0}, p1[4] = {0,0,0,0};
    #pragma unroll
    for (int c = 0; c < 8; c++) {
        int col = c * 16 + lm;
        float bcol = bA[col];
        float2 wc = ((const float2*)Wc)[col];
        #pragma unroll
        for (int r = 0; r < 4; r++) {
            float v = acc[c][r] + bcol;
            v = v > 0.f ? v : 0.f;
            p0[r] += v * wc.x;
            p1[r] += v * wc.y;
        }
    }
    #pragma unroll
    for (int off = 1; off < 16; off <<= 1) {
        #pragma unroll
        for (int r = 0; r < 4; r++) {
            p0[r] += __shfl_xor(p0[r], off);
            p1[r] += __shfl_xor(p1[r], off);
        }
    }
    if (lm == 0) {
        float b0 = bc[0], b1 = bc[1];
        #pragma unroll
        for (int r = 0; r < 4; r++) {
            int row = row0 + w * 16 + lq * 4 + r;
            if (row < n) out[row] = make_float2(p0[r] + b0, p1[r] + b1);
        }
    }
}

extern "C" void kernel_launch(void* const* d_in, const int* in_sizes, int n_in,
                              void* d_out, int out_size, void* d_ws, size_t ws_size,
                              hipStream_t stream) {
    const float* x   = (const float*)d_in[0];
    const int*   ei  = (const int*)d_in[1];
    const float* W1a = (const float*)d_in[2];
    const float* b1a = (const float*)d_in[3];
    const float* W1b = (const float*)d_in[4];
    const float* b1b = (const float*)d_in[5];
    const float* W2a = (const float*)d_in[6];
    const float* b2a = (const float*)d_in[7];
    const float* W2b = (const float*)d_in[8];
    const float* b2b = (const float*)d_in[9];
    const float* Wfc = (const float*)d_in[10];
    const float* bfc = (const float*)d_in[11];

    const int* esrc = ei;
    const int* edst = ei + N_EDGES;

    char* w = (char*)d_ws;
    size_t off = 0;
    auto alloc = [&](size_t bytes) -> char* {
        char* p = w + off;
        off = (off + bytes + 255) & ~(size_t)255;
        return p;
    };
    int2*  span       = (int2*)alloc((size_t)N_NODES * 8);
    int*   startTab   = (int*)alloc((size_t)NBUK * B_A * 4);
    int*   cntTab     = (int*)alloc((size_t)NBUK * B_A * 4);
    int*   csr        = (int*)alloc((size_t)NBUK * CAPB * 4);
    u32*   binned     = (u32*)alloc((size_t)B_A * EPB * 4);
    u16*   wt1a       = (u16*)alloc(128 * 128 * 2);
    u16*   wt1b       = (u16*)alloc(128 * 128 * 2);
    u16*   wt2a       = (u16*)alloc(128 * 128 * 2);
    float* Wc         = (float*)alloc(256 * 4);
    float* bc         = (float*)alloc(2 * 4);
    u32*   xb         = (u32*)alloc((size_t)N_NODES * 64 * 4);   // x slabs
    u32*   aggA       = (u32*)alloc((size_t)N_NODES * 64 * 4);   // agg buffers
    u16*   h1         = (u16*)alloc((size_t)N_NODES * 128 * 2);  // h1 slabs

    // 1) bin edges + convert x (slab layout) + weight prep
    binA_kernel<<<B_A + 193, 256, 0, stream>>>(esrc, edst, binned, startTab, cntTab,
                                               x, xb,
                                               W1a, W1b, W2a, W2b, Wfc, b2b, bfc,
                                               wt1a, wt1b, wt2a, Wc, bc);
    // 2) per-bucket CSR + spans
    binB_kernel<<<NBUK, 256, 0, stream>>>(binned, startTab, cntTab, span, csr);
    // 3) conv1: XCD-slab agg -> gemm(W1a,W1b)+relu -> h1 slabs
    agg_kernel<<<3128, 256, 0, stream>>>(xb, span, csr, aggA, N_NODES);
    gemm1_kernel<<<TILES, 256, 0, stream>>>(aggA, wt1a, b1a, wt1b, b1b, h1, N_NODES);
    // 4) conv2+fc: XCD-slab agg(h1) -> gemm(W2a)+relu @ Wc + bc -> out
    agg_kernel<<<3128, 256, 0, stream>>>((const u32*)h1, span, csr, aggA, N_NODES);
    gemm2fc_kernel<<<TILES, 256, 0, stream>>>(aggA, wt2a, b2a, Wc, bc,
                                              (float2*)d_out, N_NODES);
}

// Round 15
// 209.610 us; speedup vs baseline: 1.0907x; 1.0907x over previous
//
#include <hip/hip_runtime.h>

#define N_NODES 50000
#define N_EDGES 800000
#define NBUK    392          // buckets of 128 nodes: dst>>7
#define B_A     1024         // phase-A blocks
#define EPB     782          // edges per phase-A block (1024*782 >= 800000)
#define CAPB    2560         // fixed csr slot per 128-node bucket (mean 2041)

typedef unsigned short u16;
typedef unsigned int   u32;
typedef __bf16 bf16x8 __attribute__((ext_vector_type(8)));
typedef float  f32x4  __attribute__((ext_vector_type(4)));

__device__ __forceinline__ float bf_lo(u32 v){ return __uint_as_float(v << 16); }
__device__ __forceinline__ float bf_hi(u32 v){ return __uint_as_float(v & 0xffff0000u); }
__device__ __forceinline__ u32 bf_pack(float a, float b){
    u32 ua = __float_as_uint(a), ub = __float_as_uint(b);
    ua += 0x7fffu + ((ua >> 16) & 1u);
    ub += 0x7fffu + ((ub >> 16) & 1u);
    return (ua >> 16) | (ub & 0xffff0000u);
}
__device__ __forceinline__ u16 f2bf(float a){
    u32 ua = __float_as_uint(a);
    ua += 0x7fffu + ((ua >> 16) & 1u);
    return (u16)(ua >> 16);
}
__device__ __forceinline__ void addu4(uint4 v, float* a){
    a[0] += bf_lo(v.x); a[1] += bf_hi(v.x);
    a[2] += bf_lo(v.y); a[3] += bf_hi(v.y);
    a[4] += bf_lo(v.z); a[5] += bf_hi(v.z);
    a[6] += bf_lo(v.w); a[7] += bf_hi(v.w);
}

// inclusive block-scan, 256 threads (4 waves)
__device__ __forceinline__ int blockScan256(int v, int* ws, int t) {
    int lane = t & 63, w = t >> 6;
    #pragma unroll
    for (int off = 1; off < 64; off <<= 1) {
        int u = __shfl_up(v, off);
        if (lane >= off) v += u;
    }
    if (lane == 63) ws[w] = v;
    __syncthreads();
    int add = 0;
    for (int k = 0; k < w; k++) add += ws[k];
    return v + add;
}

// inclusive block-scan, 512 threads (8 waves)
__device__ __forceinline__ int blockScan512(int v, int* ws, int t) {
    int lane = t & 63, w = t >> 6;
    #pragma unroll
    for (int off = 1; off < 64; off <<= 1) {
        int u = __shfl_up(v, off);
        if (lane >= off) v += u;
    }
    if (lane == 63) ws[w] = v;
    __syncthreads();
    int add = 0;
    for (int k = 0; k < w; k++) add += ws[k];
    return v + add;
}

// ---- binA: blocks [0,1024): bucket-sort own 782 edges (dst>>7) in LDS, linear
//      flush; grid-stride fp32->bf16 of x. Blocks [1024,1217): weight prep.
//      cntTab/startTab layout: [bucket][run], stride B_A (coalesced for bconv1).
__launch_bounds__(256)
__global__ void binA_kernel(const int* __restrict__ esrc, const int* __restrict__ edst,
                            u32* __restrict__ binned, int* __restrict__ startTab,
                            int* __restrict__ cntTab,
                            const float* __restrict__ xsrc, u32* __restrict__ xb,
                            const float* __restrict__ W1a, const float* __restrict__ W1b,
                            const float* __restrict__ W2a, const float* __restrict__ W2b,
                            const float* __restrict__ Wfc, const float* __restrict__ b2b,
                            const float* __restrict__ bfc,
                            u16* __restrict__ wt1a, u16* __restrict__ wt1b,
                            u16* __restrict__ wt2a,
                            float* __restrict__ Wc, float* __restrict__ bc) {
    int t = threadIdx.x, blk = blockIdx.x;
    if (blk >= B_A) {                    // ---- prep branch (193 blocks)
        int b = blk - B_A;
        if (b < 192) {
            int g  = b * 256 + t;
            int mi = g >> 14;
            int p  = g & 16383;
            int k  = p >> 7, m = p & 127;
            const float* src = (mi == 0) ? W1a : (mi == 1) ? W1b : W2a;
            u16* dst         = (mi == 0) ? wt1a : (mi == 1) ? wt1b : wt2a;
            dst[m * 128 + k] = f2bf(src[k * 128 + m]);
        } else {
            int j = t >> 1, o = t & 1;
            float s = 0.f;
            for (int k = 0; k < 128; k++)
                s += W2b[j * 128 + k] * Wfc[k * 2 + o];
            Wc[j * 2 + o] = s;
            if (t < 2) {
                float s2 = 0.f;
                for (int k = 0; k < 128; k++)
                    s2 += b2b[k] * Wfc[k * 2 + t];
                bc[t] = s2 + bfc[t];
            }
        }
        return;
    }
    __shared__ int hist[NBUK];
    __shared__ int cur[NBUK];
    __shared__ u32 ebuf[EPB];
    __shared__ int ws[4];
    int base = blk * EPB;
    for (int i = t; i < NBUK; i += 256) hist[i] = 0;
    __syncthreads();
    for (int i = t; i < EPB; i += 256) {
        int gi = base + i;
        if (gi < N_EDGES) atomicAdd(&hist[edst[gi] >> 7], 1);
    }
    __syncthreads();
    int c0 = 0, c1 = 0;
    if (t < 196) { c0 = hist[2 * t]; c1 = hist[2 * t + 1]; }
    int s2 = c0 + c1;
    int incl = blockScan256(s2, ws, t);
    int excl = incl - s2;
    if (t < 196) {
        startTab[(2 * t) * B_A + blk]     = excl;        // [bucket][run]
        cntTab[(2 * t) * B_A + blk]       = c0;
        cur[2 * t] = excl;
        startTab[(2 * t + 1) * B_A + blk] = excl + c0;
        cntTab[(2 * t + 1) * B_A + blk]   = c1;
        cur[2 * t + 1] = excl + c0;
    }
    __syncthreads();
    for (int i = t; i < EPB; i += 256) {
        int gi = base + i;
        if (gi < N_EDGES) {
            int d = edst[gi], s = esrc[gi];
            int p = atomicAdd(&cur[d >> 7], 1);
            ebuf[p] = (u32)s | ((u32)(d & 127) << 16);   // src(16b)|dst_local(7b)
        }
    }
    __syncthreads();
    for (int i = t; i < EPB; i += 256)               // linear flush
        binned[base + i] = ebuf[i];
    const int total = N_NODES * 64;
    for (int i = blk * 256 + t; i < total; i += B_A * 256) {
        float2 f = ((const float2*)xsrc)[i];
        xb[i] = bf_pack(f.x, f.y);
    }
}

// ---- bconv1: 392 blocks x 512 threads, one 128-node bucket each.
// Phase 1 (binB): build bucket CSR in LDS; spans kept in LDS AND written to
// global (with csr) for conv2. Phase 2 (conv1): gather from LDS spans/cbuf,
// MFMA(W1a)+relu, repack, MFMA(W1b)+relu -> h1. Wave-private 16-row groups.
// NOTE: the gather is MSHR-latency-bound (~60-65us/conv floor) — verified
// invariant to occupancy (R5-7), unroll depth (R12), L2 slab capacity (R13),
// and XCD partitioning (R14).
__launch_bounds__(512, 4)
__global__ void bconv1_kernel(const u32* __restrict__ binned,
                              const int* __restrict__ startTab, const int* __restrict__ cntTab,
                              const u32* __restrict__ xb,
                              const u16* __restrict__ WA, const float* __restrict__ bA,
                              const u16* __restrict__ WB, const float* __restrict__ bB,
                              int2* __restrict__ span, int* __restrict__ csr,
                              u16* __restrict__ h1, int n) {
    __shared__ __align__(16) char shbuf[34816 + 10240 + 512 + 512 + 32 + 16];
    u16 (*As)[136] = (u16(*)[136])shbuf;                 // 34816 B (phase 2)
    u32* ebuf      = (u32*)shbuf;                        // 10240 B (phase 1, aliases As)
    int* cbuf      = (int*)(shbuf + 34816);              // 10240 B
    int* hist      = (int*)(shbuf + 34816 + 10240);      // 512 B -> span starts
    int* cursor    = (int*)(shbuf + 34816 + 10240 + 512);// 512 B -> span ends
    int* ws        = (int*)(shbuf + 34816 + 10240 + 1024);
    int* totsh     = ws + 8;
    int b = blockIdx.x, t = threadIdx.x;

    // ---- phase 1: build bucket CSR in LDS ----------------------------------
    int c2[2], rs2[2], s = 0;
    #pragma unroll
    for (int q = 0; q < 2; q++) {
        int run = t * 2 + q;
        c2[q]  = cntTab[b * B_A + run];               // coalesced
        rs2[q] = run * EPB + startTab[b * B_A + run]; // coalesced
        s += c2[q];
    }
    int incl = blockScan512(s, ws, t);
    int rb = incl - s;
    if (t == 511) *totsh = incl;
    if (t < 128) hist[t] = 0;
    __syncthreads();
    #pragma unroll
    for (int q = 0; q < 2; q++) {                     // copy own runs (no search)
        int c = c2[q], rs = rs2[q];
        for (int k = 0; k < c; k++) {
            int p = rb + k;
            if (p < CAPB) ebuf[p] = binned[rs + k];
        }
        rb += c;
    }
    __syncthreads();
    int tot = *totsh;
    if (tot > CAPB) tot = CAPB;                       // statistical guard
    for (int i = t; i < tot; i += 512)
        atomicAdd(&hist[ebuf[i] >> 16], 1);
    __syncthreads();
    int hv = (t < 128) ? hist[t] : 0;
    int hincl = blockScan512(hv, ws, t);
    int hexcl = hincl - hv;
    int gb = b * CAPB;
    if (t < 128) {
        hist[t]   = hexcl;                            // local span start
        cursor[t] = hexcl;
        int node = (b << 7) + t;
        if (node < n) span[node] = make_int2(gb + hexcl, gb + hexcl + hv);
    }
    __syncthreads();
    for (int i = t; i < tot; i += 512) {
        u32 e = ebuf[i];
        int p = atomicAdd(&cursor[e >> 16], 1);
        cbuf[p] = (int)(e & 0xFFFFu);
    }
    __syncthreads();
    for (int i = t; i < tot; i += 512)                // flush csr for conv2
        csr[gb + i] = cbuf[i];
    __syncthreads();   // ebuf dead; As may now overwrite it. hist/cursor = spans.

    // ---- phase 2: conv1 on this bucket's 128 rows --------------------------
    int row0 = b * 128;
    int w = t >> 6, lane = t & 63;                    // 8 waves
    int g4 = lane >> 4, l16 = lane & 15;
    const uint4* xp = (const uint4*)xb;
    #pragma unroll
    for (int p = 0; p < 4; p++) {                     // 4 nodes/wave/pass
        int rl = w * 16 + p * 4 + g4;                 // 0..127
        int node = row0 + rl;
        float a[8] = {0.f,0.f,0.f,0.f,0.f,0.f,0.f,0.f};
        if (node < n) {
            addu4(xp[(size_t)node * 16 + l16], a);    // self term
            int j = hist[rl], jend = cursor[rl];      // LDS spans
            for (; j + 8 <= jend; j += 8) {
                int s0 = cbuf[j],     s1 = cbuf[j + 1], s2b = cbuf[j + 2], s3 = cbuf[j + 3];
                int s4 = cbuf[j + 4], s5 = cbuf[j + 5], s6 = cbuf[j + 6], s7 = cbuf[j + 7];
                uint4 v0 = xp[(size_t)s0 * 16 + l16], v1 = xp[(size_t)s1 * 16 + l16];
                uint4 v2 = xp[(size_t)s2b * 16 + l16], v3 = xp[(size_t)s3 * 16 + l16];
                uint4 v4 = xp[(size_t)s4 * 16 + l16], v5 = xp[(size_t)s5 * 16 + l16];
                uint4 v6 = xp[(size_t)s6 * 16 + l16], v7 = xp[(size_t)s7 * 16 + l16];
                addu4(v0, a); addu4(v1, a); addu4(v2, a); addu4(v3, a);
                addu4(v4, a); addu4(v5, a); addu4(v6, a); addu4(v7, a);
            }
            for (; j + 4 <= jend; j += 4) {
                int s0 = cbuf[j], s1 = cbuf[j + 1], s2b = cbuf[j + 2], s3 = cbuf[j + 3];
                uint4 v0 = xp[(size_t)s0 * 16 + l16], v1 = xp[(size_t)s1 * 16 + l16];
                uint4 v2 = xp[(size_t)s2b * 16 + l16], v3 = xp[(size_t)s3 * 16 + l16];
                addu4(v0, a); addu4(v1, a); addu4(v2, a); addu4(v3, a);
            }
            for (; j < jend; j++)
                addu4(xp[(size_t)cbuf[j] * 16 + l16], a);
        }
        uint4 pk = make_uint4(bf_pack(a[0], a[1]), bf_pack(a[2], a[3]),
                              bf_pack(a[4], a[5]), bf_pack(a[6], a[7]));
        *(uint4*)&As[rl][l16 * 8] = pk;
    }
    // no barrier: wave w reads only rows w*16..w*16+15, which it wrote
    int lm = l16, lq = g4;
    f32x4 acc[8];
    #pragma unroll
    for (int c = 0; c < 8; c++) acc[c] = (f32x4){0.f, 0.f, 0.f, 0.f};
    #pragma unroll
    for (int kk = 0; kk < 4; kk++) {
        bf16x8 af = *(const bf16x8*)&As[w * 16 + lm][kk * 32 + lq * 8];
        #pragma unroll
        for (int c = 0; c < 8; c++) {
            bf16x8 bf = *(const bf16x8*)(WA + (size_t)(c * 16 + lm) * 128 + kk * 32 + lq * 8);
            acc[c] = __builtin_amdgcn_mfma_f32_16x16x32_bf16(af, bf, acc[c], 0, 0, 0);
        }
    }
    #pragma unroll
    for (int c = 0; c < 8; c++) {
        int col = c * 16 + lm;
        float bcol = bA[col];
        #pragma unroll
        for (int r = 0; r < 4; r++) {
            float v = acc[c][r] + bcol;
            v = v > 0.f ? v : 0.f;
            As[w * 16 + lq * 4 + r][col] = f2bf(v);
        }
    }
    f32x4 acc2[8];
    #pragma unroll
    for (int c = 0; c < 8; c++) acc2[c] = (f32x4){0.f, 0.f, 0.f, 0.f};
    #pragma unroll
    for (int kk = 0; kk < 4; kk++) {
        bf16x8 af = *(const bf16x8*)&As[w * 16 + lm][kk * 32 + lq * 8];
        #pragma unroll
        for (int c = 0; c < 8; c++) {
            bf16x8 bf = *(const bf16x8*)(WB + (size_t)(c * 16 + lm) * 128 + kk * 32 + lq * 8);
            acc2[c] = __builtin_amdgcn_mfma_f32_16x16x32_bf16(af, bf, acc2[c], 0, 0, 0);
        }
    }
    #pragma unroll
    for (int c = 0; c < 8; c++) {
        int col = c * 16 + lm;
        float bcol = bB[col];
        #pragma unroll
        for (int r = 0; r < 4; r++) {
            int row = row0 + w * 16 + lq * 4 + r;
            if (row < n) {
                float v = acc2[c][r] + bcol;
                v = v > 0.f ? v : 0.f;
                h1[(size_t)row * 128 + col] = f2bf(v);
            }
        }
    }
}

// ---- fconv2: conv2+FC (782 blocks x 256 threads) ---------------------------
__launch_bounds__(256, 4)
__global__ void fconv2_kernel(const u32* __restrict__ xb,
                              const u16* __restrict__ WA, const float* __restrict__ bA,
                              const float* __restrict__ Wc, const float* __restrict__ bc,
                              const int2* __restrict__ span, const int* __restrict__ csr,
                              float2* __restrict__ out, int n) {
    __shared__ u16 As[64][136];
    int t = threadIdx.x;
    int row0 = blockIdx.x * 64;
    int w = t >> 6, lane = t & 63;
    int g4 = lane >> 4, l16 = lane & 15;
    const uint4* xp = (const uint4*)xb;
    #pragma unroll
    for (int p = 0; p < 4; p++) {
        int rl = w * 16 + p * 4 + g4;
        int node = row0 + rl;
        float a[8] = {0.f,0.f,0.f,0.f,0.f,0.f,0.f,0.f};
        if (node < n) {
            addu4(xp[(size_t)node * 16 + l16], a);
            int2 sp = span[node];
            int j = sp.x, jend = sp.y;
            for (; j + 8 <= jend; j += 8) {
                int s0 = csr[j],     s1 = csr[j + 1], s2 = csr[j + 2], s3 = csr[j + 3];
                int s4 = csr[j + 4], s5 = csr[j + 5], s6 = csr[j + 6], s7 = csr[j + 7];
                uint4 v0 = xp[(size_t)s0 * 16 + l16], v1 = xp[(size_t)s1 * 16 + l16];
                uint4 v2 = xp[(size_t)s2 * 16 + l16], v3 = xp[(size_t)s3 * 16 + l16];
                uint4 v4 = xp[(size_t)s4 * 16 + l16], v5 = xp[(size_t)s5 * 16 + l16];
                uint4 v6 = xp[(size_t)s6 * 16 + l16], v7 = xp[(size_t)s7 * 16 + l16];
                addu4(v0, a); addu4(v1, a); addu4(v2, a); addu4(v3, a);
                addu4(v4, a); addu4(v5, a); addu4(v6, a); addu4(v7, a);
            }
            for (; j + 4 <= jend; j += 4) {
                int s0 = csr[j], s1 = csr[j + 1], s2 = csr[j + 2], s3 = csr[j + 3];
                uint4 v0 = xp[(size_t)s0 * 16 + l16], v1 = xp[(size_t)s1 * 16 + l16];
                uint4 v2 = xp[(size_t)s2 * 16 + l16], v3 = xp[(size_t)s3 * 16 + l16];
                addu4(v0, a); addu4(v1, a); addu4(v2, a); addu4(v3, a);
            }
            for (; j < jend; j++)
                addu4(xp[(size_t)csr[j] * 16 + l16], a);
        }
        uint4 pk = make_uint4(bf_pack(a[0], a[1]), bf_pack(a[2], a[3]),
                              bf_pack(a[4], a[5]), bf_pack(a[6], a[7]));
        *(uint4*)&As[rl][l16 * 8] = pk;
    }
    int lm = l16, lq = g4;
    f32x4 acc[8];
    #pragma unroll
    for (int c = 0; c < 8; c++) acc[c] = (f32x4){0.f, 0.f, 0.f, 0.f};
    #pragma unroll
    for (int kk = 0; kk < 4; kk++) {
        bf16x8 af = *(const bf16x8*)&As[w * 16 + lm][kk * 32 + lq * 8];
        #pragma unroll
        for (int c = 0; c < 8; c++) {
            bf16x8 bf = *(const bf16x8*)(WA + (size_t)(c * 16 + lm) * 128 + kk * 32 + lq * 8);
            acc[c] = __builtin_amdgcn_mfma_f32_16x16x32_bf16(af, bf, acc[c], 0, 0, 0);
        }
    }
    float p0[4] = {0,0,0,0}, p1[4] = {0,0,0,0};
    #pragma unroll
    for (int c = 0; c < 8; c++) {
        int col = c * 16 + lm;
        float bcol = bA[col];
        float2 wc = ((const float2*)Wc)[col];
        #pragma unroll
        for (int r = 0; r < 4; r++) {
            float v = acc[c][r] + bcol;
            v = v > 0.f ? v : 0.f;
            p0[r] += v * wc.x;
            p1[r] += v * wc.y;
        }
    }
    #pragma unroll
    for (int off = 1; off < 16; off <<= 1) {
        #pragma unroll
        for (int r = 0; r < 4; r++) {
            p0[r] += __shfl_xor(p0[r], off);
            p1[r] += __shfl_xor(p1[r], off);
        }
    }
    if (lm == 0) {
        float b0 = bc[0], b1 = bc[1];
        #pragma unroll
        for (int r = 0; r < 4; r++) {
            int row = row0 + w * 16 + lq * 4 + r;
            if (row < n) out[row] = make_float2(p0[r] + b0, p1[r] + b1);
        }
    }
}

extern "C" void kernel_launch(void* const* d_in, const int* in_sizes, int n_in,
                              void* d_out, int out_size, void* d_ws, size_t ws_size,
                              hipStream_t stream) {
    const float* x   = (const float*)d_in[0];
    const int*   ei  = (const int*)d_in[1];
    const float* W1a = (const float*)d_in[2];
    const float* b1a = (const float*)d_in[3];
    const float* W1b = (const float*)d_in[4];
    const float* b1b = (const float*)d_in[5];
    const float* W2a = (const float*)d_in[6];
    const float* b2a = (const float*)d_in[7];
    const float* W2b = (const float*)d_in[8];
    const float* b2b = (const float*)d_in[9];
    const float* Wfc = (const float*)d_in[10];
    const float* bfc = (const float*)d_in[11];

    const int* esrc = ei;
    const int* edst = ei + N_EDGES;

    char* w = (char*)d_ws;
    size_t off = 0;
    auto alloc = [&](size_t bytes) -> char* {
        char* p = w + off;
        off = (off + bytes + 255) & ~(size_t)255;
        return p;
    };
    int2*  span       = (int2*)alloc((size_t)N_NODES * 8);
    int*   startTab   = (int*)alloc((size_t)NBUK * B_A * 4);
    int*   cntTab     = (int*)alloc((size_t)NBUK * B_A * 4);
    int*   csr        = (int*)alloc((size_t)NBUK * CAPB * 4);
    u32*   binned     = (u32*)alloc((size_t)B_A * EPB * 4);
    u16*   wt1a       = (u16*)alloc(128 * 128 * 2);
    u16*   wt1b       = (u16*)alloc(128 * 128 * 2);
    u16*   wt2a       = (u16*)alloc(128 * 128 * 2);
    float* Wc         = (float*)alloc(256 * 4);
    float* bc         = (float*)alloc(2 * 4);
    u16*   bufA       = (u16*)alloc((size_t)N_NODES * 128 * 2);   // h1
    u16*   bufB       = (u16*)alloc((size_t)N_NODES * 128 * 2);   // xb

    // 1) bin edges + convert x + weight prep
    binA_kernel<<<B_A + 193, 256, 0, stream>>>(esrc, edst, binned, startTab, cntTab,
                                               x, (u32*)bufB,
                                               W1a, W1b, W2a, W2b, Wfc, b2b, bfc,
                                               wt1a, wt1b, wt2a, Wc, bc);
    // 2) per-bucket CSR (LDS) + conv1 MLP fused -> h1 (also writes span/csr)
    bconv1_kernel<<<NBUK, 512, 0, stream>>>(binned, startTab, cntTab,
                                            (const u32*)bufB, wt1a, b1a, wt1b, b1b,
                                            span, csr, bufA, N_NODES);
    // 3) conv2 + folded FC -> d_out (fp32)
    fconv2_kernel<<<(N_NODES + 63) / 64, 256, 0, stream>>>((const u32*)bufA, wt2a, b2a,
                                                           Wc, bc, span, csr,
                                                           (float2*)d_out, N_NODES);
}